// Round 7
// baseline (361.666 us; speedup 1.0000x reference)
//
#include <hip/hip_runtime.h>
#include <math.h>

// VectorExpansion: out[l, p, n] = sin(pi*x*n)/max(r,eps) * fc(r) * sqrt(2/rc) * x^l
// x = r/rc, rc=5, n=1..8, l=0..3.  fp32 in / fp32 out (verified R3).
//
// R7 theory: the R3/R4 single-pass was slow because ALL stores were
// data-dependent on the gather->sqrt chain; the R5 fill kernel was fast
// because its stores have no dependencies. So: one kernel, zero-stores
// issued FIRST (addresses from p only -> saturate store BW immediately),
// then the ~3% inside-cutoff lanes overwrite their rows with values.
// Same-lane same-address stores are program-order sequenced -> correct.

#define RC_INV 0.2f
#define NORM 0.6324555320336759f  /* sqrt(2/5) */

struct f3u { float x, y, z; };   // 12 B packed -> global_load_dwordx3

__global__ __launch_bounds__(256) void ve_fused(
    const f3u* __restrict__ positions,          // [N] packed float3
    const float* __restrict__ cells,            // [S,3,3] fp32
    const int* __restrict__ cell_shifts,        // [P,3]
    const int* __restrict__ pairs,              // [P,2]
    const int* __restrict__ structure_pairs,    // [P]
    const int* __restrict__ structure_offsets,  // [S]
    float* __restrict__ out,                    // [4,P,8] fp32
    int P)
{
    const int p = blockIdx.x * blockDim.x + threadIdx.x;
    if (p >= P) return;

    // ---- phase 1: dependency-free zero stores of this pair's 4 rows ----
    float4* out4 = (float4*)out;
    const float4 z = make_float4(0.f, 0.f, 0.f, 0.f);
    long long base[4];
    #pragma unroll
    for (int l = 0; l < 4; ++l) {
        base[l] = 2LL * (1LL*l*P + p);
        out4[base[l] + 0] = z;
        out4[base[l] + 1] = z;
    }

    // ---- phase 2: pair geometry ----
    const int s   = structure_pairs[p];
    const int off = structure_offsets[s];       // S=32 table, L1-resident
    const int2 pr = ((const int2*)pairs)[p];

    const f3u pj = positions[off + pr.y];       // dwordx3 gather (L2-resident)
    const f3u pi = positions[off + pr.x];

    const float shx = (float)cell_shifts[3*p + 0];
    const float shy = (float)cell_shifts[3*p + 1];
    const float shz = (float)cell_shifts[3*p + 2];

    const float* C = cells + 9*s;               // row-major [c][d], L1-resident
    const float vx = pj.x - pi.x + shx*C[0] + shy*C[3] + shz*C[6];
    const float vy = pj.y - pi.y + shx*C[1] + shy*C[4] + shz*C[7];
    const float vz = pj.z - pi.z + shx*C[2] + shy*C[5] + shz*C[8];

    const float d2 = vx*vx + vy*vy + vz*vz + 1e-12f;
    const float r  = __builtin_amdgcn_sqrtf(d2);
    const float x  = r * RC_INV;

    if (x >= 1.0f) return;                      // fc==0 -> rows stay zero

    // ---- phase 3 (~3% of lanes): values overwrite the zeros ----
    // sin(pi*x) = v_sin(x/2) (HW trig, arg in revolutions; no range reduction)
    const float s1 = __builtin_amdgcn_sinf(0.5f * x);
    const float c1 = __builtin_amdgcn_cosf(0.5f * x);
    const float fc = 0.5f * (c1 + 1.0f);
    const float pref = fc * NORM * __builtin_amdgcn_rcpf(r);

    // sin(n*pi*x) by Chebyshev: s_{n+1} = 2*cos(pi*x)*s_n - s_{n-1}
    float b[8];
    {
        float sm1 = 0.0f, sn = s1;
        const float twoc = 2.0f * c1;
        #pragma unroll
        for (int n = 0; n < 8; ++n) {
            b[n] = pref * sn;
            const float nxt = twoc * sn - sm1;
            sm1 = sn; sn = nxt;
        }
    }

    float xl = 1.0f;
    #pragma unroll
    for (int l = 0; l < 4; ++l) {
        out4[base[l] + 0] = make_float4(b[0]*xl, b[1]*xl, b[2]*xl, b[3]*xl);
        out4[base[l] + 1] = make_float4(b[4]*xl, b[5]*xl, b[6]*xl, b[7]*xl);
        xl *= x;
    }
}

extern "C" void kernel_launch(void* const* d_in, const int* in_sizes, int n_in,
                              void* d_out, int out_size, void* d_ws, size_t ws_size,
                              hipStream_t stream) {
    const f3u*   positions         = (const f3u*)d_in[0];
    const float* cells             = (const float*)d_in[1];
    const int*   cell_shifts       = (const int*)d_in[3];
    const int*   pairs             = (const int*)d_in[5];
    const int*   structure_pairs   = (const int*)d_in[7];
    const int*   structure_offsets = (const int*)d_in[8];
    float*       out               = (float*)d_out;

    const int P = in_sizes[7];          // structure_pairs is [P]
    const int block = 256;
    ve_fused<<<(P + block - 1) / block, block, 0, stream>>>(
        positions, cells, cell_shifts, pairs,
        structure_pairs, structure_offsets, out, P);
}

// Round 8
// 355.984 us; speedup vs baseline: 1.0160x; 1.0160x over previous
//
#include <hip/hip_runtime.h>
#include <math.h>

// VectorExpansion: out[l, p, n] = sin(pi*x*n)/max(r,eps) * fc(r) * sqrt(2/rc) * x^l
// x = r/rc, rc=5, n=1..8, l=0..3.  fp32 in / fp32 out (verified R3).
//
// R8: fused fill+compute, contiguous-store edition.
//  R7 post-mortem: per-pair zero stores (stride-2 float4 across the wave)
//  half-write each 64B line per instr -> 2x store transactions -> +30us.
//  Fix: block b's 256 pairs own contiguous float4 slots [2*l*P+512*b, +512)
//  per slab. Phase 1 zero-fills that region with wave-contiguous full-line
//  stores (same pattern as the 6.3 TB/s fill kernel). Phase 2 issues pair
//  loads (independent -> overlap under store drain). __syncthreads() (emits
//  s_waitcnt vmcnt(0) before s_barrier) orders zero->value same-address
//  stores across threads of the block. Phase 3: ~3% lanes overwrite.

#define RC_INV 0.2f
#define NORM 0.6324555320336759f  /* sqrt(2/5) */

struct f3u { float x, y, z; };   // 12 B packed -> global_load_dwordx3

__global__ __launch_bounds__(256) void ve_fused(
    const f3u* __restrict__ positions,          // [N] packed float3
    const float* __restrict__ cells,            // [S,3,3] fp32
    const int* __restrict__ cell_shifts,        // [P,3]
    const int* __restrict__ pairs,              // [P,2]
    const int* __restrict__ structure_pairs,    // [P]
    const int* __restrict__ structure_offsets,  // [S]
    float* __restrict__ out,                    // [4,P,8] fp32
    int P)
{
    const int tid = threadIdx.x;
    const int p   = blockIdx.x * blockDim.x + tid;
    float4* out4  = (float4*)out;

    // ---- phase 1: wave-contiguous zero-fill of this block's region ----
    {
        const float4 z = make_float4(0.f, 0.f, 0.f, 0.f);
        const long long blockBase = 512LL * blockIdx.x;  // float4 slots per slab
        #pragma unroll
        for (int l = 0; l < 4; ++l) {
            const long long slab = 2LL * l * P;
            const long long i0 = blockBase + tid;
            const long long i1 = blockBase + 256 + tid;
            if (i0 < 2LL * P) out4[slab + i0] = z;
            if (i1 < 2LL * P) out4[slab + i1] = z;
        }
    }

    // ---- phase 2: pair loads (independent of the stores above) ----
    float vx = 0.f, vy = 0.f, vz = 0.f;
    bool in_range = (p < P);
    if (in_range) {
        const int s   = structure_pairs[p];
        const int off = structure_offsets[s];   // S=32 table, L1-resident
        const int2 pr = ((const int2*)pairs)[p];
        const f3u pj = positions[off + pr.y];   // dwordx3 gather (L2-resident)
        const f3u pi = positions[off + pr.x];
        const float shx = (float)cell_shifts[3*p + 0];
        const float shy = (float)cell_shifts[3*p + 1];
        const float shz = (float)cell_shifts[3*p + 2];
        const float* C = cells + 9*s;           // row-major [c][d], L1-resident
        vx = pj.x - pi.x + shx*C[0] + shy*C[3] + shz*C[6];
        vy = pj.y - pi.y + shx*C[1] + shy*C[4] + shz*C[7];
        vz = pj.z - pi.z + shx*C[2] + shy*C[5] + shz*C[8];
    }

    // Drains vmcnt(0): zero-stores visible in L2, loads complete.
    __syncthreads();

    if (!in_range) return;

    const float d2 = vx*vx + vy*vy + vz*vz + 1e-12f;
    const float r  = __builtin_amdgcn_sqrtf(d2);
    const float x  = r * RC_INV;
    if (x >= 1.0f) return;                      // fc==0 -> rows stay zero

    // ---- phase 3 (~3% of lanes): values overwrite the zeros ----
    // sin(pi*x) = v_sin(x/2) (HW trig, arg in revolutions; no range reduction)
    const float s1 = __builtin_amdgcn_sinf(0.5f * x);
    const float c1 = __builtin_amdgcn_cosf(0.5f * x);
    const float fc = 0.5f * (c1 + 1.0f);
    const float pref = fc * NORM * __builtin_amdgcn_rcpf(r);

    // sin(n*pi*x) by Chebyshev: s_{n+1} = 2*cos(pi*x)*s_n - s_{n-1}
    float b[8];
    {
        float sm1 = 0.0f, sn = s1;
        const float twoc = 2.0f * c1;
        #pragma unroll
        for (int n = 0; n < 8; ++n) {
            b[n] = pref * sn;
            const float nxt = twoc * sn - sm1;
            sm1 = sn; sn = nxt;
        }
    }

    float xl = 1.0f;
    #pragma unroll
    for (int l = 0; l < 4; ++l) {
        const long long base = 2LL * (1LL*l*P + p);
        out4[base + 0] = make_float4(b[0]*xl, b[1]*xl, b[2]*xl, b[3]*xl);
        out4[base + 1] = make_float4(b[4]*xl, b[5]*xl, b[6]*xl, b[7]*xl);
        xl *= x;
    }
}

extern "C" void kernel_launch(void* const* d_in, const int* in_sizes, int n_in,
                              void* d_out, int out_size, void* d_ws, size_t ws_size,
                              hipStream_t stream) {
    const f3u*   positions         = (const f3u*)d_in[0];
    const float* cells             = (const float*)d_in[1];
    const int*   cell_shifts       = (const int*)d_in[3];
    const int*   pairs             = (const int*)d_in[5];
    const int*   structure_pairs   = (const int*)d_in[7];
    const int*   structure_offsets = (const int*)d_in[8];
    float*       out               = (float*)d_out;

    const int P = in_sizes[7];          // structure_pairs is [P]
    const int block = 256;
    ve_fused<<<(P + block - 1) / block, block, 0, stream>>>(
        positions, cells, cell_shifts, pairs,
        structure_pairs, structure_offsets, out, P);
}

// Round 9
// 349.200 us; speedup vs baseline: 1.0357x; 1.0194x over previous
//
#include <hip/hip_runtime.h>
#include <math.h>

// VectorExpansion: out[l, p, n] = sin(pi*x*n)/max(r,eps) * fc(r) * sqrt(2/rc) * x^l
// x = r/rc, rc=5, n=1..8, l=0..3.  fp32 in / fp32 out (verified R3).
//
// R9: disjoint-address fusion.
//  R8 post-mortem: fused fill+overwrite needs __syncthreads AFTER the zero
//  stores -> vmcnt(0) drain of 8 stores/wave serializes on the 268MB write
//  stream (88us vs split's 64us). Fix: compute inside-cutoff flags FIRST,
//  share via LDS, then zero-fill PREDICATES OFF the ~3% value slots while
//  value lanes write exactly those slots. Zero/value addresses are disjoint
//  -> no store ordering needed; the single barrier precedes all stores
//  (only consumed loads outstanding -> cheap drain).
//  Fill keeps wave-contiguous full-line stores (R7 lesson: strided 16B
//  stores half-fill 64B lines -> 2x store transactions).

#define RC_INV 0.2f
#define NORM 0.6324555320336759f  /* sqrt(2/5) */

struct f3u { float x, y, z; };   // 12 B packed -> global_load_dwordx3
struct i3u { int   x, y, z; };   // 12 B packed -> global_load_dwordx3

__global__ __launch_bounds__(256) void ve_fused(
    const f3u* __restrict__ positions,          // [N] packed float3
    const float* __restrict__ cells,            // [S,3,3] fp32
    const i3u* __restrict__ cell_shifts,        // [P] packed int3
    const int* __restrict__ pairs,              // [P,2]
    const int* __restrict__ structure_pairs,    // [P]
    const int* __restrict__ structure_offsets,  // [S]
    float* __restrict__ out,                    // [4,P,8] fp32
    int P)
{
    __shared__ int sFlag[256];                  // 1 = inside cutoff (value row)

    const int tid = threadIdx.x;
    const int p   = blockIdx.x * blockDim.x + tid;
    float4* out4  = (float4*)out;

    // ---- phase A: own pair geometry -> inside flag ----
    float r = 1.0f, x = 2.0f;                   // defaults: outside
    if (p < P) {
        const int s   = structure_pairs[p];
        const int off = structure_offsets[s];   // S=32 table, L1-resident
        const int2 pr = ((const int2*)pairs)[p];
        const f3u pj = positions[off + pr.y];   // dwordx3 gather (L2-resident)
        const f3u pi = positions[off + pr.x];
        const i3u sh = cell_shifts[p];          // one dwordx3
        const float shx = (float)sh.x, shy = (float)sh.y, shz = (float)sh.z;
        const float* C = cells + 9*s;           // row-major [c][d], L1-resident
        const float vx = pj.x - pi.x + shx*C[0] + shy*C[3] + shz*C[6];
        const float vy = pj.y - pi.y + shx*C[1] + shy*C[4] + shz*C[7];
        const float vz = pj.z - pi.z + shx*C[2] + shy*C[5] + shz*C[8];
        const float d2 = vx*vx + vy*vy + vz*vz + 1e-12f;
        r = __builtin_amdgcn_sqrtf(d2);
        x = r * RC_INV;
    }
    const bool inside = (x < 1.0f);
    sFlag[tid] = inside ? 1 : 0;

    // Only consumed loads + one LDS write outstanding -> cheap drain.
    __syncthreads();

    // ---- phase B: predicated wave-contiguous zero-fill of block's region ----
    // Block region per slab: float4 slots [2*l*P + 512*blk, +512).
    // Region slot j belongs to pair 256*blk + (j>>1).
    {
        const float4 z = make_float4(0.f, 0.f, 0.f, 0.f);
        const long long blockBase = 512LL * blockIdx.x;
        const int f0 = tid >> 1;                // pair (in-block) for slot tid
        const int f1 = 128 + (tid >> 1);        // pair for slot 256+tid
        const bool skip0 = sFlag[f0];           // value lane owns that slot
        const bool skip1 = sFlag[f1];
        #pragma unroll
        for (int l = 0; l < 4; ++l) {
            const long long slab = 2LL * l * P;
            const long long i0 = blockBase + tid;
            const long long i1 = blockBase + 256 + tid;
            if (!skip0 && i0 < 2LL * P) out4[slab + i0] = z;
            if (!skip1 && i1 < 2LL * P) out4[slab + i1] = z;
        }
    }

    // ---- phase C (~3% of lanes): value rows (disjoint from phase B) ----
    if (!inside) return;

    // sin(pi*x) = v_sin(x/2) (HW trig, arg in revolutions; no range reduction)
    const float s1 = __builtin_amdgcn_sinf(0.5f * x);
    const float c1 = __builtin_amdgcn_cosf(0.5f * x);
    const float fc = 0.5f * (c1 + 1.0f);
    const float pref = fc * NORM * __builtin_amdgcn_rcpf(r);

    // sin(n*pi*x) by Chebyshev: s_{n+1} = 2*cos(pi*x)*s_n - s_{n-1}
    float b[8];
    {
        float sm1 = 0.0f, sn = s1;
        const float twoc = 2.0f * c1;
        #pragma unroll
        for (int n = 0; n < 8; ++n) {
            b[n] = pref * sn;
            const float nxt = twoc * sn - sm1;
            sm1 = sn; sn = nxt;
        }
    }

    float xl = 1.0f;
    #pragma unroll
    for (int l = 0; l < 4; ++l) {
        const long long base = 2LL * (1LL*l*P + p);
        out4[base + 0] = make_float4(b[0]*xl, b[1]*xl, b[2]*xl, b[3]*xl);
        out4[base + 1] = make_float4(b[4]*xl, b[5]*xl, b[6]*xl, b[7]*xl);
        xl *= x;
    }
}

extern "C" void kernel_launch(void* const* d_in, const int* in_sizes, int n_in,
                              void* d_out, int out_size, void* d_ws, size_t ws_size,
                              hipStream_t stream) {
    const f3u*   positions         = (const f3u*)d_in[0];
    const float* cells             = (const float*)d_in[1];
    const i3u*   cell_shifts       = (const i3u*)d_in[3];
    const int*   pairs             = (const int*)d_in[5];
    const int*   structure_pairs   = (const int*)d_in[7];
    const int*   structure_offsets = (const int*)d_in[8];
    float*       out               = (float*)d_out;

    const int P = in_sizes[7];          // structure_pairs is [P]
    const int block = 256;
    ve_fused<<<(P + block - 1) / block, block, 0, stream>>>(
        positions, cells, cell_shifts, pairs,
        structure_pairs, structure_offsets, out, P);
}

// Round 10
// 332.761 us; speedup vs baseline: 1.0869x; 1.0494x over previous
//
#include <hip/hip_runtime.h>
#include <math.h>

// VectorExpansion: out[l, p, n] = sin(pi*x*n)/max(r,eps) * fc(r) * sqrt(2/rc) * x^l
// x = r/rc, rc=5, n=1..8, l=0..3.  fp32 in / fp32 out (verified R3).
//
// Final structure = R5 split (fusion attempts R7-R9 all lost ~17-30us to
// HBM read/write turnaround: the pure-write fill dispatch runs at the
// 6.3 TB/s ceiling precisely because no reads interleave).
//  kernel 1: zero-fill d_out (268 MB @ ~6.3 TB/s ~= 43us).
//  kernel 2: sparse pair pass, 2 pairs/thread (int2/int4/dwordx3 streamed
//   loads, 4 position gathers); only ~3% inside-cutoff lanes do trig+stores.

#define RC_INV 0.2f
#define NORM 0.6324555320336759f  /* sqrt(2/5) */

struct f3u { float x, y, z; };   // 12 B packed -> global_load_dwordx3
struct i3u { int   x, y, z; };   // 12 B packed -> global_load_dwordx3

__global__ __launch_bounds__(256) void zero_fill4(float4* __restrict__ out, int n4) {
    const int i = blockIdx.x * blockDim.x + threadIdx.x;
    if (i < n4) out[i] = make_float4(0.f, 0.f, 0.f, 0.f);
}

__device__ __forceinline__ void ve_one(
    int p, int s, int off, int2 pr, i3u sh,
    const f3u* __restrict__ positions, const float* __restrict__ cells,
    float4* __restrict__ out4, int P)
{
    const f3u pj = positions[off + pr.y];       // dwordx3 gather (L2-resident)
    const f3u pi = positions[off + pr.x];
    const float shx = (float)sh.x, shy = (float)sh.y, shz = (float)sh.z;
    const float* C = cells + 9*s;               // row-major [c][d], L1-resident
    const float vx = pj.x - pi.x + shx*C[0] + shy*C[3] + shz*C[6];
    const float vy = pj.y - pi.y + shx*C[1] + shy*C[4] + shz*C[7];
    const float vz = pj.z - pi.z + shx*C[2] + shy*C[5] + shz*C[8];

    const float d2 = vx*vx + vy*vy + vz*vz + 1e-12f;
    const float r  = __builtin_amdgcn_sqrtf(d2);
    const float x  = r * RC_INV;
    if (x >= 1.0f) return;                      // fc==0 -> row already zeroed

    // sin(pi*x) = v_sin(x/2) (HW trig, arg in revolutions; no range reduction)
    const float s1 = __builtin_amdgcn_sinf(0.5f * x);
    const float c1 = __builtin_amdgcn_cosf(0.5f * x);
    const float fc = 0.5f * (c1 + 1.0f);
    const float pref = fc * NORM * __builtin_amdgcn_rcpf(r);

    // sin(n*pi*x) by Chebyshev: s_{n+1} = 2*cos(pi*x)*s_n - s_{n-1}
    float b[8];
    float sm1 = 0.0f, sn = s1;
    const float twoc = 2.0f * c1;
    #pragma unroll
    for (int n = 0; n < 8; ++n) {
        b[n] = pref * sn;
        const float nxt = twoc * sn - sm1;
        sm1 = sn; sn = nxt;
    }

    float xl = 1.0f;
    #pragma unroll
    for (int l = 0; l < 4; ++l) {
        const long long base = 2LL * (1LL*l*P + p);
        out4[base + 0] = make_float4(b[0]*xl, b[1]*xl, b[2]*xl, b[3]*xl);
        out4[base + 1] = make_float4(b[4]*xl, b[5]*xl, b[6]*xl, b[7]*xl);
        xl *= x;
    }
}

__global__ __launch_bounds__(256) void ve_sparse2(
    const f3u* __restrict__ positions,          // [N] packed float3
    const float* __restrict__ cells,            // [S,3,3] fp32
    const i3u* __restrict__ cell_shifts,        // [P] packed int3
    const int* __restrict__ pairs,              // [P,2]
    const int* __restrict__ structure_pairs,    // [P]
    const int* __restrict__ structure_offsets,  // [S]
    float* __restrict__ out,                    // [4,P,8] fp32 (pre-zeroed)
    int P)
{
    const int g = blockIdx.x * blockDim.x + threadIdx.x;
    const int p0 = 2 * g;
    if (p0 >= P) return;

    const int2 ss = ((const int2*)structure_pairs)[g];   // s for p0, p0+1
    const int4 pq = ((const int4*)pairs)[g];             // pairs for p0, p0+1
    const i3u sh0 = cell_shifts[p0];
    const i3u sh1 = cell_shifts[p0 + 1];
    const int off0 = structure_offsets[ss.x];            // S=32 table, L1-resident
    const int off1 = structure_offsets[ss.y];

    float4* out4 = (float4*)out;
    ve_one(p0,     ss.x, off0, make_int2(pq.x, pq.y), sh0, positions, cells, out4, P);
    ve_one(p0 + 1, ss.y, off1, make_int2(pq.z, pq.w), sh1, positions, cells, out4, P);
}

extern "C" void kernel_launch(void* const* d_in, const int* in_sizes, int n_in,
                              void* d_out, int out_size, void* d_ws, size_t ws_size,
                              hipStream_t stream) {
    const f3u*   positions         = (const f3u*)d_in[0];
    const float* cells             = (const float*)d_in[1];
    const i3u*   cell_shifts       = (const i3u*)d_in[3];
    const int*   pairs             = (const int*)d_in[5];
    const int*   structure_pairs   = (const int*)d_in[7];
    const int*   structure_offsets = (const int*)d_in[8];
    float*       out               = (float*)d_out;

    const int P = in_sizes[7];          // structure_pairs is [P], even
    const int block = 256;

    const int n4 = out_size / 4;        // out_size = 4*P*8, divisible by 4
    zero_fill4<<<(n4 + block - 1) / block, block, 0, stream>>>((float4*)out, n4);

    const int nthread = P / 2;
    ve_sparse2<<<(nthread + block - 1) / block, block, 0, stream>>>(
        positions, cells, cell_shifts, pairs,
        structure_pairs, structure_offsets, out, P);
}